// Round 12
// baseline (70.237 us; speedup 1.0000x reference)
//
#include <hip/hip_runtime.h>
#include <hip/hip_cooperative_groups.h>

// GNNEmbeds: 3-layer NNConv, scalar edge features.
// W(e) = attr_e*A + B  =>  msg_e = attr_e*(h[src]@A) + (h[src]@B)
// Per layer: U = h@A, V = h@B, R = h@root + bias; h_next = relu(R + gather(U,V)).
// Round-12: ONE cooperative dispatch, per-tile flag sync (NO grid.sync — R9
// measured it at ~27us each due to L2 writeback-invalidate).
//  - Producers write U/V with sc0|sc1 stores (write-through to coherence point,
//    per-XCD L2s are not coherent), vmcnt(0), then set an agent-scope flag.
//  - Consumers spin (bounded) on all tile flags with relaxed agent atomic
//    loads, then gather U/V with sc0|sc1 loads (immune to stale L2 lines).
//  - Edge scan runs ONCE; list lives in LDS across all 3 phases. R-term lives
//    in LDS rs (never round-trips). Layer-1 via cheap P/Q trick (in_c=2).
//  - Layers 2/3 keep R10's proven U/V gather + 16-group JIT-batch GEMM.

#define HD    128
#define TR    4          // dst rows per tile -> N=1024 gives 256 blocks (1/CU)
#define CAP   192        // LDS edge-list capacity (mean 32/tile; proven)
#define CAPP  (CAP + 16)
#define NTHR  512
#define SCR   TR         // scratch row for pad-edge dummies
#define KSPL  4
#define TOKEN 0x7F3A9C51u

typedef float f4 __attribute__((ext_vector_type(4)));

struct Tile {
    float hs[TR + 1][HD];               // gather accumulator (+ scratch row)
    float rs[TR][HD];                   // own-tile R term, phase-carried
    float pbuf[KSPL - 1][3][TR][HD];    // GEMM partials
    float p1q1[2][TR + 1][2];           // layer-1 P,Q (in_c=2)
    int   lrow[CAPP];
    int   lsrc[CAPP];
    float lattr[CAPP];
    int   lcnt;
};

struct P {
    const float* x; const int* ei; const float* attr;
    const float *lw1, *lb1, *root1, *bias1;
    const float *lw2, *lb2, *root2, *bias2;
    const float *lw3, *lb3, *root3, *bias3;
    float *U2, *V2, *U3, *V3, *out;
    unsigned *flagA, *flagB;
    int N, E;
};

__device__ __forceinline__ void fma4(f4& a, float s, f4 w) {
    a.x = fmaf(s, w.x, a.x); a.y = fmaf(s, w.y, a.y);
    a.z = fmaf(s, w.z, a.z); a.w = fmaf(s, w.w, a.w);
}

__device__ __forceinline__ void store4_sc1(float* p, f4 v) {
    asm volatile("global_store_dwordx4 %0, %1, off sc0 sc1"
                 :: "v"(p), "v"(v) : "memory");
}

__device__ __forceinline__ void set_flag(unsigned* f) {
    __hip_atomic_store(f, TOKEN, __ATOMIC_RELAXED, __HIP_MEMORY_SCOPE_AGENT);
}

// Spin (bounded) until all n flags carry TOKEN; then block barrier.
__device__ __forceinline__ void wait_flags(unsigned* flags, int n, int t) {
    for (int i = t; i < n; i += NTHR) {
        int guard = 0;
        while (__hip_atomic_load(&flags[i], __ATOMIC_RELAXED,
                                 __HIP_MEMORY_SCOPE_AGENT) != TOKEN) {
            __builtin_amdgcn_s_sleep(2);
            if (++guard > (1 << 20)) break;   // safety valve: fail visibly, no hang
        }
    }
    __syncthreads();
}

// Scan edges once (R10 body): dst int4, src/attr loaded on match; list padded
// to multiple of 16 with scratch-row dummies. First barrier orders prior init.
__device__ __forceinline__ int scan_edges(const int* __restrict__ ei,
                                          const float* __restrict__ attr,
                                          int E, int n0, Tile& g, int t)
{
    if (t == 0) g.lcnt = 0;
    __syncthreads();
    const int nq = E >> 2;
    const int4*   src4 = (const int4*)ei;
    const int4*   dst4 = (const int4*)(ei + E);
    const float4* at4  = (const float4*)attr;
#pragma unroll 4
    for (int i = t; i < nq; i += NTHR) {
        const int4 d = dst4[i];
        const unsigned r0 = (unsigned)(d.x - n0);
        const unsigned r1 = (unsigned)(d.y - n0);
        const unsigned r2 = (unsigned)(d.z - n0);
        const unsigned r3 = (unsigned)(d.w - n0);
        if ((r0 < TR) || (r1 < TR) || (r2 < TR) || (r3 < TR)) {
            const int4   s = src4[i];
            const float4 a = at4[i];
            if (r0 < TR) { int k = atomicAdd(&g.lcnt, 1); if (k < CAP) { g.lrow[k] = r0; g.lsrc[k] = s.x; g.lattr[k] = a.x; } }
            if (r1 < TR) { int k = atomicAdd(&g.lcnt, 1); if (k < CAP) { g.lrow[k] = r1; g.lsrc[k] = s.y; g.lattr[k] = a.y; } }
            if (r2 < TR) { int k = atomicAdd(&g.lcnt, 1); if (k < CAP) { g.lrow[k] = r2; g.lsrc[k] = s.z; g.lattr[k] = a.z; } }
            if (r3 < TR) { int k = atomicAdd(&g.lcnt, 1); if (k < CAP) { g.lrow[k] = r3; g.lsrc[k] = s.w; g.lattr[k] = a.w; } }
        }
    }
    for (int e = (E & ~3) + t; e < E; e += NTHR) {   // E%4 tail (empty here)
        const unsigned r = (unsigned)(ei[E + e] - n0);
        if (r < TR) { int k = atomicAdd(&g.lcnt, 1); if (k < CAP) { g.lrow[k] = r; g.lsrc[k] = ei[e]; g.lattr[k] = attr[e]; } }
    }
    __syncthreads();
    int cnt = g.lcnt; if (cnt > CAP) cnt = CAP;
    const int pad = (cnt + 15) & ~15;
    if (t < pad - cnt) {
        const int k = cnt + t;
        g.lrow[k] = SCR; g.lsrc[k] = 0; g.lattr[k] = 0.f;
    }
    __syncthreads();
    return pad;
}

// hs[r] += a*U[s] + V[s]; 16 edges in flight x f4 lanes; sc0|sc1 loads so
// freshly produced (other-XCD) data is read from the coherence point.
__device__ __forceinline__ void gather_uv_sc1(const float* __restrict__ U,
                                              const float* __restrict__ V,
                                              Tile& g, int pad, int t)
{
    const int el = t >> 5;
    const int c4 = (t & 31) << 2;
    for (int base = 0; base < pad; base += 16) {
        const int   i = base + el;
        const int   r = g.lrow[i];
        const int   s = g.lsrc[i];
        const float a = g.lattr[i];
        const float* pu = U + (size_t)s * HD + c4;
        const float* pv = V + (size_t)s * HD + c4;
        f4 u, v;
        asm volatile("global_load_dwordx4 %0, %2, off sc0 sc1\n\t"
                     "global_load_dwordx4 %1, %3, off sc0 sc1\n\t"
                     "s_waitcnt vmcnt(0)"
                     : "=&v"(u), "=&v"(v) : "v"(pu), "v"(pv) : "memory");
        atomicAdd(&g.hs[r][c4 + 0], fmaf(a, u.x, v.x));
        atomicAdd(&g.hs[r][c4 + 1], fmaf(a, u.y, v.y));
        atomicAdd(&g.hs[r][c4 + 2], fmaf(a, u.z, v.z));
        atomicAdd(&g.hs[r][c4 + 3], fmaf(a, u.w, v.w));
    }
    __syncthreads();
}

// GEMM (R10 body): 16 groups = (kq,row); JIT 8-k-row weight batches x3 mats
// (24 independent loads in flight); pbuf partial reduce; relu on the h-read.
// U,V -> global via sc1 stores; R(+bias) -> LDS rs.
template <bool RELU>
__device__ __forceinline__ void gemm3(Tile& g, int n0, int t,
    const float* __restrict__ Wa, const float* __restrict__ Wb,
    const float* __restrict__ Wr, const float* __restrict__ bias,
    float* __restrict__ U, float* __restrict__ V)
{
    const int colg = (t & 31) << 2;
    const int grp  = t >> 5;
    const int row  = grp & (TR - 1);
    const int kq   = grp >> 2;
    const int k0   = kq * (HD / KSPL);

    f4 acc0 = {0.f, 0.f, 0.f, 0.f};
    f4 acc1 = {0.f, 0.f, 0.f, 0.f};
    f4 acc2 = {0.f, 0.f, 0.f, 0.f};

#pragma unroll 1
    for (int kb = 0; kb < HD / KSPL; kb += 8) {
        const int kk = k0 + kb;
        f4 wav[8], wbv[8], wrv[8];
#pragma unroll
        for (int j = 0; j < 8; ++j) {
            const size_t o = (size_t)(kk + j) * HD + colg;
            wav[j] = *(const f4*)(Wa + o);
            wbv[j] = *(const f4*)(Wb + o);
            wrv[j] = *(const f4*)(Wr + o);
        }
        float hreg[8];
#pragma unroll
        for (int j = 0; j < 8; j += 4) {
            f4 h4 = *(const f4*)&g.hs[row][kk + j];
            if (RELU) {
                h4.x = fmaxf(h4.x, 0.f); h4.y = fmaxf(h4.y, 0.f);
                h4.z = fmaxf(h4.z, 0.f); h4.w = fmaxf(h4.w, 0.f);
            }
            *(f4*)&hreg[j] = h4;
        }
#pragma unroll
        for (int j = 0; j < 8; ++j) {
            fma4(acc0, hreg[j], wav[j]);
            fma4(acc1, hreg[j], wbv[j]);
            fma4(acc2, hreg[j], wrv[j]);
        }
    }

    if (kq != 0) {
        *(f4*)&g.pbuf[kq - 1][0][row][colg] = acc0;
        *(f4*)&g.pbuf[kq - 1][1][row][colg] = acc1;
        *(f4*)&g.pbuf[kq - 1][2][row][colg] = acc2;
    }
    __syncthreads();
    if (kq == 0) {
#pragma unroll
        for (int pp = 0; pp < KSPL - 1; ++pp) {
            acc0 += *(const f4*)&g.pbuf[pp][0][row][colg];
            acc1 += *(const f4*)&g.pbuf[pp][1][row][colg];
            acc2 += *(const f4*)&g.pbuf[pp][2][row][colg];
        }
        acc2 += *(const f4*)(bias + colg);
        const size_t o = (size_t)(n0 + row) * HD + colg;
        store4_sc1(U + o, acc0);
        store4_sc1(V + o, acc1);
        *(f4*)&g.rs[row][colg] = acc2;
        asm volatile("s_waitcnt vmcnt(0)" ::: "memory");   // stores at coherence pt
    }
    __syncthreads();
}

__global__ __launch_bounds__(NTHR) void fused(P p) {
    __shared__ Tile g;
    const int t = threadIdx.x;
    const int bid = blockIdx.x;
    const int n0 = bid * TR;
    const int ntiles = p.N / TR;

    // ============ Phase A: scan + layer-1 (P/Q trick) + layer-2 GEMM ============
    if (t < 2 * (TR + 1) * 2) ((float*)g.p1q1)[t] = 0.f;

    const int pad = scan_edges(p.ei, p.attr, p.E, n0, g, t);   // list persists

    for (int i = t; i < pad; i += NTHR) {        // P1,Q1: 2 comps per edge
        const int r = g.lrow[i], s = g.lsrc[i];
        const float a = g.lattr[i];
        const float2 xv = *(const float2*)(p.x + (size_t)s * 2);
        atomicAdd(&g.p1q1[0][r][0], a * xv.x);
        atomicAdd(&g.p1q1[0][r][1], a * xv.y);
        atomicAdd(&g.p1q1[1][r][0], xv.x);
        atomicAdd(&g.p1q1[1][r][1], xv.y);
    }
    __syncthreads();

    {   // hs = h1 = relu( x@root1 + bias1 + P@A1 + Q@B1 )   (TR*HD == NTHR)
        const int r = t >> 7, c = t & 127;
        const float x0 = p.x[(n0 + r) * 2 + 0], x1 = p.x[(n0 + r) * 2 + 1];
        float v = fmaf(x0, p.root1[c], fmaf(x1, p.root1[HD + c], p.bias1[c]));
        v = fmaf(g.p1q1[0][r][0], p.lw1[c],      v);
        v = fmaf(g.p1q1[0][r][1], p.lw1[HD + c], v);
        v = fmaf(g.p1q1[1][r][0], p.lb1[c],      v);
        v = fmaf(g.p1q1[1][r][1], p.lb1[HD + c], v);
        g.hs[r][c] = fmaxf(v, 0.f);
    }
    __syncthreads();

    gemm3<false>(g, n0, t, p.lw2, p.lb2, p.root2, p.bias2, p.U2, p.V2);
    if (t == 0) set_flag(&p.flagA[bid]);

    // ============ Phase B: wait flagsA; gather U2,V2; layer-3 GEMM ============
    if (t < TR * HD / 4)
        ((f4*)&g.hs[0][0])[t] = ((const f4*)&g.rs[0][0])[t];
    wait_flags(p.flagA, ntiles, t);             // includes __syncthreads

    gather_uv_sc1(p.U2, p.V2, g, pad, t);
    gemm3<true>(g, n0, t, p.lw3, p.lb3, p.root3, p.bias3, p.U3, p.V3);
    if (t == 0) set_flag(&p.flagB[bid]);

    // ============ Phase C: wait flagsB; gather U3,V3 -> out ============
    if (t < TR * HD / 4)
        ((f4*)&g.hs[0][0])[t] = ((const f4*)&g.rs[0][0])[t];
    wait_flags(p.flagB, ntiles, t);

    gather_uv_sc1(p.U3, p.V3, g, pad, t);

    if (t < TR * HD / 4)
        ((f4*)(p.out + (size_t)n0 * HD))[t] = ((const f4*)&g.hs[0][0])[t];
}

extern "C" void kernel_launch(void* const* d_in, const int* in_sizes, int n_in,
                              void* d_out, int out_size, void* d_ws, size_t ws_size,
                              hipStream_t stream) {
    P p;
    p.x     = (const float*)d_in[0];
    p.ei    = (const int*)  d_in[1];
    p.attr  = (const float*)d_in[2];
    p.lw1   = (const float*)d_in[3];
    p.lb1   = (const float*)d_in[4];
    p.root1 = (const float*)d_in[5];
    p.bias1 = (const float*)d_in[6];
    p.lw2   = (const float*)d_in[7];
    p.lb2   = (const float*)d_in[8];
    p.root2 = (const float*)d_in[9];
    p.bias2 = (const float*)d_in[10];
    p.lw3   = (const float*)d_in[11];
    p.lb3   = (const float*)d_in[12];
    p.root3 = (const float*)d_in[13];
    p.bias3 = (const float*)d_in[14];

    p.N = in_sizes[0] / 2;   // x: [N,2]
    p.E = in_sizes[1] / 2;   // edge_index: [2,E]
    const int ntiles = p.N / TR;   // 256 blocks, 1 per CU

    float* ws = (float*)d_ws;
    p.U2 = ws + 0 * (size_t)p.N * HD;
    p.V2 = ws + 1 * (size_t)p.N * HD;
    p.U3 = ws + 2 * (size_t)p.N * HD;
    p.V3 = ws + 3 * (size_t)p.N * HD;
    p.flagA = (unsigned*)(ws + 4 * (size_t)p.N * HD);
    p.flagB = p.flagA + ntiles;
    p.out = (float*)d_out;

    void* args[] = { &p };
    hipLaunchCooperativeKernel((const void*)fused, dim3(ntiles), dim3(NTHR),
                               args, 0, stream);
}

// Round 14
// 47.367 us; speedup vs baseline: 1.4828x; 1.4828x over previous
//
#include <hip/hip_runtime.h>

// GNNEmbeds: 3-layer NNConv, scalar edge features.
// W(e) = attr_e*A + B  =>  msg_e = attr_e*(h[src]@A) + (h[src]@B)
// Per layer: U = h@A, V = h@B, R = h@root + bias; h_next = relu(R + gather(msgs)).
// 3 dispatches (structural minimum; grid.sync ~27us (R9), single-dispatch
// spin-sync failed validation (R13)), gather-into-consumer, no global atomics.
// Round-14 = R10 (best passing, 56.5us) + ONE validated delta:
//  - Layer-1 via P/Q identity (validated in R12): sum_e attr*(x@A1)+x@B1
//    = P@A1 + Q@B1 with P,Q = [4][2] per-tile sums (in_c=2). Replaces g2k's
//    128-wide per-edge message gather with 4 scalar LDS atomics/edge.
//  - Everything else (scan, persist-lists, gather, 16-group GEMM) = R10 verbatim.

#define HD    128
#define TR    4          // dst rows per tile -> N=1024 gives 256 blocks (1/CU)
#define CAP   192        // LDS edge-list capacity (mean 32/tile)
#define CAPP  (CAP + 16) // padded stride for persisted lists
#define NTHR  512
#define SCR   TR         // scratch row for pad edges
#define KSPL  4

struct Tile {
    float hs[TR + 1][HD];               // gather accumulator (+ scratch row)
    float pbuf[KSPL - 1][3][TR][HD];    // GEMM partials
    float p1q1[2][TR + 1][2];           // layer-1 P,Q sums (+ scratch row)
    int   lrow[CAPP];
    int   lsrc[CAPP];
    float lattr[CAPP];
    int   lcnt;
};

__device__ __forceinline__ void fma4(float4& a, float s, const float4& w) {
    a.x = fmaf(s, w.x, a.x); a.y = fmaf(s, w.y, a.y);
    a.z = fmaf(s, w.z, a.z); a.w = fmaf(s, w.w, a.w);
}

// Scan edges (g2k only; proven body): dst int4, src/attr loaded on match; list
// padded to multiple of 16 with scratch-row dummies. First barrier also orders
// the caller's preceding LDS init writes.
__device__ __forceinline__ int scan_edges(const int* __restrict__ ei,
                                          const float* __restrict__ attr,
                                          int E, int n0, Tile& g, int t)
{
    if (t == 0) g.lcnt = 0;
    __syncthreads();
    const int nq = E >> 2;
    const int4*   src4 = (const int4*)ei;
    const int4*   dst4 = (const int4*)(ei + E);
    const float4* at4  = (const float4*)attr;
#pragma unroll 4
    for (int i = t; i < nq; i += NTHR) {
        const int4 d = dst4[i];
        const unsigned r0 = (unsigned)(d.x - n0);
        const unsigned r1 = (unsigned)(d.y - n0);
        const unsigned r2 = (unsigned)(d.z - n0);
        const unsigned r3 = (unsigned)(d.w - n0);
        if ((r0 < TR) || (r1 < TR) || (r2 < TR) || (r3 < TR)) {
            const int4   s = src4[i];
            const float4 a = at4[i];
            if (r0 < TR) { int k = atomicAdd(&g.lcnt, 1); if (k < CAP) { g.lrow[k] = r0; g.lsrc[k] = s.x; g.lattr[k] = a.x; } }
            if (r1 < TR) { int k = atomicAdd(&g.lcnt, 1); if (k < CAP) { g.lrow[k] = r1; g.lsrc[k] = s.y; g.lattr[k] = a.y; } }
            if (r2 < TR) { int k = atomicAdd(&g.lcnt, 1); if (k < CAP) { g.lrow[k] = r2; g.lsrc[k] = s.z; g.lattr[k] = a.z; } }
            if (r3 < TR) { int k = atomicAdd(&g.lcnt, 1); if (k < CAP) { g.lrow[k] = r3; g.lsrc[k] = s.w; g.lattr[k] = a.w; } }
        }
    }
    for (int e = (E & ~3) + t; e < E; e += NTHR) {   // E%4 tail (empty here)
        const unsigned r = (unsigned)(ei[E + e] - n0);
        if (r < TR) { int k = atomicAdd(&g.lcnt, 1); if (k < CAP) { g.lrow[k] = r; g.lsrc[k] = ei[e]; g.lattr[k] = attr[e]; } }
    }
    __syncthreads();
    int cnt = g.lcnt; if (cnt > CAP) cnt = CAP;
    const int pad = (cnt + 15) & ~15;
    if (t < pad - cnt) {
        const int k = cnt + t;
        g.lrow[k] = SCR; g.lsrc[k] = 0; g.lattr[k] = 0.f;
    }
    __syncthreads();
    return pad;
}

// hs[r] += a*U[s] + V[s]; 16 edges in flight x float4 lanes. (proven body)
__device__ __forceinline__ void gather_uv(const float* __restrict__ U,
                                          const float* __restrict__ V,
                                          Tile& g, int pad, int t)
{
    const int el = t >> 5;
    const int c4 = (t & 31) << 2;
#pragma unroll 2
    for (int base = 0; base < pad; base += 16) {
        const int   i = base + el;
        const int   r = g.lrow[i];
        const int   s = g.lsrc[i];
        const float a = g.lattr[i];
        const float4 u = *(const float4*)(U + (size_t)s * HD + c4);
        const float4 v = *(const float4*)(V + (size_t)s * HD + c4);
        atomicAdd(&g.hs[r][c4 + 0], fmaf(a, u.x, v.x));
        atomicAdd(&g.hs[r][c4 + 1], fmaf(a, u.y, v.y));
        atomicAdd(&g.hs[r][c4 + 2], fmaf(a, u.z, v.z));
        atomicAdd(&g.hs[r][c4 + 3], fmaf(a, u.w, v.w));
    }
    __syncthreads();
}

// GEMM (R6/R10 body): 16 groups = (kq,row); KB=8 JIT weight batches
// (24 independent float4 in flight); pbuf partial reduce; relu on the h-read.
template <bool RELU>
__device__ __forceinline__ void gemm3(Tile& g, int n0, int t,
    const float* __restrict__ Wa, const float* __restrict__ Wb,
    const float* __restrict__ Wr, const float* __restrict__ bias,
    float* __restrict__ U, float* __restrict__ V, float* __restrict__ R)
{
    const int colg = (t & 31) << 2;
    const int grp  = t >> 5;
    const int row  = grp & (TR - 1);
    const int kq   = grp >> 2;
    const int k0   = kq * (HD / KSPL);

    float4 acc0 = make_float4(0.f, 0.f, 0.f, 0.f);
    float4 acc1 = make_float4(0.f, 0.f, 0.f, 0.f);
    float4 acc2 = make_float4(0.f, 0.f, 0.f, 0.f);

#pragma unroll 1
    for (int kb = 0; kb < HD / KSPL; kb += 8) {
        const int kk = k0 + kb;
        float4 wav[8], wbv[8], wrv[8];
#pragma unroll
        for (int j = 0; j < 8; ++j) {
            const size_t o = (size_t)(kk + j) * HD + colg;
            wav[j] = *(const float4*)(Wa + o);
            wbv[j] = *(const float4*)(Wb + o);
            wrv[j] = *(const float4*)(Wr + o);
        }
        float hreg[8];
#pragma unroll
        for (int j = 0; j < 8; j += 4) {
            float4 h4 = *(const float4*)&g.hs[row][kk + j];
            if (RELU) {
                h4.x = fmaxf(h4.x, 0.f); h4.y = fmaxf(h4.y, 0.f);
                h4.z = fmaxf(h4.z, 0.f); h4.w = fmaxf(h4.w, 0.f);
            }
            *(float4*)&hreg[j] = h4;
        }
#pragma unroll
        for (int j = 0; j < 8; ++j) {
            fma4(acc0, hreg[j], wav[j]);
            fma4(acc1, hreg[j], wbv[j]);
            fma4(acc2, hreg[j], wrv[j]);
        }
    }

    if (kq != 0) {
        *(float4*)&g.pbuf[kq - 1][0][row][colg] = acc0;
        *(float4*)&g.pbuf[kq - 1][1][row][colg] = acc1;
        *(float4*)&g.pbuf[kq - 1][2][row][colg] = acc2;
    }
    __syncthreads();
    if (kq == 0) {
#pragma unroll
        for (int pp = 0; pp < KSPL - 1; ++pp) {
            const float4 p0 = *(const float4*)&g.pbuf[pp][0][row][colg];
            const float4 p1 = *(const float4*)&g.pbuf[pp][1][row][colg];
            const float4 p2 = *(const float4*)&g.pbuf[pp][2][row][colg];
            acc0.x += p0.x; acc0.y += p0.y; acc0.z += p0.z; acc0.w += p0.w;
            acc1.x += p1.x; acc1.y += p1.y; acc1.z += p1.z; acc1.w += p1.w;
            acc2.x += p2.x; acc2.y += p2.y; acc2.z += p2.z; acc2.w += p2.w;
        }
        const float4 bv = *(const float4*)(bias + colg);
        acc2.x += bv.x; acc2.y += bv.y; acc2.z += bv.z; acc2.w += bv.w;
        const size_t o = (size_t)(n0 + row) * HD + colg;
        *(float4*)(U + o) = acc0;
        *(float4*)(V + o) = acc1;
        *(float4*)(R + o) = acc2;
    }
}

// ---- G2: scan + persist + layer-1 via P/Q identity + layer-2 GEMMs ----
__global__ __launch_bounds__(NTHR) void g2k(
    const float* __restrict__ x, const int* __restrict__ ei,
    const float* __restrict__ attr,
    const float* __restrict__ lw1, const float* __restrict__ lb1,
    const float* __restrict__ root1, const float* __restrict__ bias1,
    const float* __restrict__ lw2, const float* __restrict__ lb2,
    const float* __restrict__ root2, const float* __restrict__ bias2,
    float* __restrict__ U2, float* __restrict__ V2, float* __restrict__ R2,
    int* __restrict__ gecnt, int* __restrict__ gerow,
    int* __restrict__ gesrc, float* __restrict__ geattr,
    int E)
{
    __shared__ Tile g;
    const int t = threadIdx.x;
    const int n0 = blockIdx.x * TR;

    // zero P/Q sums (ordered before use by scan's first barrier)
    if (t < 2 * (TR + 1) * 2) ((float*)g.p1q1)[t] = 0.f;

    const int pad = scan_edges(ei, attr, E, n0, g, t);

    // persist padded list for g3k/g4k (plain global stores)
    {
        const int base = blockIdx.x * CAPP;
        if (t < pad) {
            gerow[base + t]  = g.lrow[t];
            gesrc[base + t]  = g.lsrc[t];
            geattr[base + t] = g.lattr[t];
        }
        if (t == 0) gecnt[blockIdx.x] = pad;
    }

    // P1,Q1 sums: P[r] += a*x[s], Q[r] += x[s]  (2 components each)
    for (int i = t; i < pad; i += NTHR) {
        const int r = g.lrow[i], s = g.lsrc[i];
        const float a = g.lattr[i];
        const float2 xv = *(const float2*)(x + (size_t)s * 2);
        atomicAdd(&g.p1q1[0][r][0], a * xv.x);
        atomicAdd(&g.p1q1[0][r][1], a * xv.y);
        atomicAdd(&g.p1q1[1][r][0], xv.x);
        atomicAdd(&g.p1q1[1][r][1], xv.y);
    }
    __syncthreads();

    // hs = h1 = relu( x@root1 + bias1 + P@A1 + Q@B1 )   (TR*HD == NTHR)
    {
        const int r = t >> 7, c = t & 127;
        const float x0 = x[(n0 + r) * 2 + 0], x1 = x[(n0 + r) * 2 + 1];
        float v = fmaf(x0, root1[c], fmaf(x1, root1[HD + c], bias1[c]));
        v = fmaf(g.p1q1[0][r][0], lw1[c],      v);
        v = fmaf(g.p1q1[0][r][1], lw1[HD + c], v);
        v = fmaf(g.p1q1[1][r][0], lb1[c],      v);
        v = fmaf(g.p1q1[1][r][1], lb1[HD + c], v);
        g.hs[r][c] = fmaxf(v, 0.f);
    }
    __syncthreads();

    gemm3<false>(g, n0, t, lw2, lb2, root2, bias2, U2, V2, R2);
}

// ---- G3: list-load + layer-2 gather + layer-3 GEMMs ----
__global__ __launch_bounds__(NTHR) void g3k(
    const float* __restrict__ U2, const float* __restrict__ V2,
    const float* __restrict__ R2,
    const float* __restrict__ lw3, const float* __restrict__ lb3,
    const float* __restrict__ root3, const float* __restrict__ bias3,
    float* __restrict__ U3, float* __restrict__ V3, float* __restrict__ R3,
    const int* __restrict__ gecnt, const int* __restrict__ gerow,
    const int* __restrict__ gesrc, const float* __restrict__ geattr)
{
    __shared__ Tile g;
    const int t = threadIdx.x;
    const int n0 = blockIdx.x * TR;

    // hs-init and list-load overlap; one shared barrier.
    if (t < TR * HD / 4)
        ((float4*)&g.hs[0][0])[t] = ((const float4*)(R2 + (size_t)n0 * HD))[t];
    const int pad = gecnt[blockIdx.x];
    {
        const int base = blockIdx.x * CAPP;
        if (t < pad) {
            g.lrow[t]  = gerow[base + t];
            g.lsrc[t]  = gesrc[base + t];
            g.lattr[t] = geattr[base + t];
        }
    }
    __syncthreads();

    gather_uv(U2, V2, g, pad, t);
    gemm3<true>(g, n0, t, lw3, lb3, root3, bias3, U3, V3, R3);
}

// ---- G4: list-load + layer-3 gather -> out (no relu, plain stores) ----
__global__ __launch_bounds__(NTHR) void g4k(
    const float* __restrict__ U3, const float* __restrict__ V3,
    const float* __restrict__ R3, float* __restrict__ out,
    const int* __restrict__ gecnt, const int* __restrict__ gerow,
    const int* __restrict__ gesrc, const float* __restrict__ geattr)
{
    __shared__ Tile g;
    const int t = threadIdx.x;
    const int n0 = blockIdx.x * TR;

    if (t < TR * HD / 4)
        ((float4*)&g.hs[0][0])[t] = ((const float4*)(R3 + (size_t)n0 * HD))[t];
    const int pad = gecnt[blockIdx.x];
    {
        const int base = blockIdx.x * CAPP;
        if (t < pad) {
            g.lrow[t]  = gerow[base + t];
            g.lsrc[t]  = gesrc[base + t];
            g.lattr[t] = geattr[base + t];
        }
    }
    __syncthreads();

    gather_uv(U3, V3, g, pad, t);

    if (t < TR * HD / 4)
        ((float4*)(out + (size_t)n0 * HD))[t] = ((const float4*)&g.hs[0][0])[t];
}

extern "C" void kernel_launch(void* const* d_in, const int* in_sizes, int n_in,
                              void* d_out, int out_size, void* d_ws, size_t ws_size,
                              hipStream_t stream) {
    const float* x     = (const float*)d_in[0];
    const int*   ei    = (const int*)  d_in[1];
    const float* attr  = (const float*)d_in[2];
    const float* lw1   = (const float*)d_in[3];
    const float* lb1   = (const float*)d_in[4];
    const float* root1 = (const float*)d_in[5];
    const float* bias1 = (const float*)d_in[6];
    const float* lw2   = (const float*)d_in[7];
    const float* lb2   = (const float*)d_in[8];
    const float* root2 = (const float*)d_in[9];
    const float* bias2 = (const float*)d_in[10];
    const float* lw3   = (const float*)d_in[11];
    const float* lb3   = (const float*)d_in[12];
    const float* root3 = (const float*)d_in[13];
    const float* bias3 = (const float*)d_in[14];

    const int N = in_sizes[0] / 2;   // x: [N,2]
    const int E = in_sizes[1] / 2;   // edge_index: [2,E]
    const int ntiles = N / TR;       // 256 blocks, ~1 per CU

    float* out = (float*)d_out;
    float* ws  = (float*)d_ws;
    float* U2 = ws + 0 * (size_t)N * HD;
    float* V2 = ws + 1 * (size_t)N * HD;
    float* R2 = ws + 2 * (size_t)N * HD;
    float* U3 = ws + 3 * (size_t)N * HD;
    float* V3 = ws + 4 * (size_t)N * HD;
    float* R3 = ws + 5 * (size_t)N * HD;
    int*   gecnt  = (int*)(ws + 6 * (size_t)N * HD);
    int*   gerow  = gecnt + ntiles;
    int*   gesrc  = gerow + (size_t)ntiles * CAPP;
    float* geattr = (float*)(gesrc + (size_t)ntiles * CAPP);

    g2k<<<ntiles, NTHR, 0, stream>>>(x, ei, attr, lw1, lb1, root1, bias1,
                                     lw2, lb2, root2, bias2, U2, V2, R2,
                                     gecnt, gerow, gesrc, geattr, E);
    g3k<<<ntiles, NTHR, 0, stream>>>(U2, V2, R2, lw3, lb3, root3, bias3,
                                     U3, V3, R3, gecnt, gerow, gesrc, geattr);
    g4k<<<ntiles, NTHR, 0, stream>>>(U3, V3, R3, out,
                                     gecnt, gerow, gesrc, geattr);
}

// Round 15
// 42.776 us; speedup vs baseline: 1.6420x; 1.1073x over previous
//
#include <hip/hip_runtime.h>

// GNNEmbeds: 3-layer NNConv, scalar edge features.
// W(e) = attr_e*A + B  =>  msg_e = attr_e*(h[src]@A) + (h[src]@B)
// Per layer: U = h@A, V = h@B, R = h@root + bias; h_next = relu(R + gather(msgs)).
// 3 dispatches (structural minimum; grid.sync ~27us (R9), single-dispatch
// spin-sync failed validation (R13)), gather-into-consumer, no global atomics.
// Round-15 = R14 (best, 47.4us) + ONE delta: weight-once GEMM.
//  - gemm3: 12 groups = (mat m, k-quarter kq); each group computes ALL 4 rows
//    for its 32 k-rows -> every weight element read ONCE per block
//    (768KB -> 192KB L2 traffic). 16-deep JIT weight batches. pbuf reduce
//    (no LDS atomics, no zeroing pass -- the R8 variant's overheads removed).
//  - Everything else (scan, persist-lists, P/Q layer-1, gather) = R14 verbatim.

#define HD    128
#define TR    4          // dst rows per tile -> N=1024 gives 256 blocks (1/CU)
#define CAP   192        // LDS edge-list capacity (mean 32/tile)
#define CAPP  (CAP + 16) // padded stride for persisted lists
#define NTHR  512
#define SCR   TR         // scratch row for pad edges

struct Tile {
    float hs[TR + 1][HD];           // gather accumulator (+ scratch row)
    float pbuf[3][3][TR][HD];       // GEMM partials [kq-1][mat][row][col]
    float p1q1[2][TR + 1][2];       // layer-1 P,Q sums (+ scratch row)
    int   lrow[CAPP];
    int   lsrc[CAPP];
    float lattr[CAPP];
    int   lcnt;
};

__device__ __forceinline__ void fma4(float4& a, float s, const float4& w) {
    a.x = fmaf(s, w.x, a.x); a.y = fmaf(s, w.y, a.y);
    a.z = fmaf(s, w.z, a.z); a.w = fmaf(s, w.w, a.w);
}

// Scan edges (g2k only; proven body): dst int4, src/attr loaded on match; list
// padded to multiple of 16 with scratch-row dummies. First barrier also orders
// the caller's preceding LDS init writes.
__device__ __forceinline__ int scan_edges(const int* __restrict__ ei,
                                          const float* __restrict__ attr,
                                          int E, int n0, Tile& g, int t)
{
    if (t == 0) g.lcnt = 0;
    __syncthreads();
    const int nq = E >> 2;
    const int4*   src4 = (const int4*)ei;
    const int4*   dst4 = (const int4*)(ei + E);
    const float4* at4  = (const float4*)attr;
#pragma unroll 4
    for (int i = t; i < nq; i += NTHR) {
        const int4 d = dst4[i];
        const unsigned r0 = (unsigned)(d.x - n0);
        const unsigned r1 = (unsigned)(d.y - n0);
        const unsigned r2 = (unsigned)(d.z - n0);
        const unsigned r3 = (unsigned)(d.w - n0);
        if ((r0 < TR) || (r1 < TR) || (r2 < TR) || (r3 < TR)) {
            const int4   s = src4[i];
            const float4 a = at4[i];
            if (r0 < TR) { int k = atomicAdd(&g.lcnt, 1); if (k < CAP) { g.lrow[k] = r0; g.lsrc[k] = s.x; g.lattr[k] = a.x; } }
            if (r1 < TR) { int k = atomicAdd(&g.lcnt, 1); if (k < CAP) { g.lrow[k] = r1; g.lsrc[k] = s.y; g.lattr[k] = a.y; } }
            if (r2 < TR) { int k = atomicAdd(&g.lcnt, 1); if (k < CAP) { g.lrow[k] = r2; g.lsrc[k] = s.z; g.lattr[k] = a.z; } }
            if (r3 < TR) { int k = atomicAdd(&g.lcnt, 1); if (k < CAP) { g.lrow[k] = r3; g.lsrc[k] = s.w; g.lattr[k] = a.w; } }
        }
    }
    for (int e = (E & ~3) + t; e < E; e += NTHR) {   // E%4 tail (empty here)
        const unsigned r = (unsigned)(ei[E + e] - n0);
        if (r < TR) { int k = atomicAdd(&g.lcnt, 1); if (k < CAP) { g.lrow[k] = r; g.lsrc[k] = ei[e]; g.lattr[k] = attr[e]; } }
    }
    __syncthreads();
    int cnt = g.lcnt; if (cnt > CAP) cnt = CAP;
    const int pad = (cnt + 15) & ~15;
    if (t < pad - cnt) {
        const int k = cnt + t;
        g.lrow[k] = SCR; g.lsrc[k] = 0; g.lattr[k] = 0.f;
    }
    __syncthreads();
    return pad;
}

// hs[r] += a*U[s] + V[s]; 16 edges in flight x float4 lanes. (proven body)
__device__ __forceinline__ void gather_uv(const float* __restrict__ U,
                                          const float* __restrict__ V,
                                          Tile& g, int pad, int t)
{
    const int el = t >> 5;
    const int c4 = (t & 31) << 2;
#pragma unroll 2
    for (int base = 0; base < pad; base += 16) {
        const int   i = base + el;
        const int   r = g.lrow[i];
        const int   s = g.lsrc[i];
        const float a = g.lattr[i];
        const float4 u = *(const float4*)(U + (size_t)s * HD + c4);
        const float4 v = *(const float4*)(V + (size_t)s * HD + c4);
        atomicAdd(&g.hs[r][c4 + 0], fmaf(a, u.x, v.x));
        atomicAdd(&g.hs[r][c4 + 1], fmaf(a, u.y, v.y));
        atomicAdd(&g.hs[r][c4 + 2], fmaf(a, u.z, v.z));
        atomicAdd(&g.hs[r][c4 + 3], fmaf(a, u.w, v.w));
    }
    __syncthreads();
}

// GEMM (weight-once): 12 groups of 32 lanes = (mat m in 0..2, k-quarter kq).
// Each group computes ALL TR rows for its 32 k-rows -> each weight element is
// read exactly once per block. 16-deep JIT weight batches. Groups 12..15 idle
// through the compute (still hit both barriers). pbuf reduce by kq==0 groups.
template <bool RELU>
__device__ __forceinline__ void gemm3(Tile& g, int n0, int t,
    const float* __restrict__ Wa, const float* __restrict__ Wb,
    const float* __restrict__ Wr, const float* __restrict__ bias,
    float* __restrict__ U, float* __restrict__ V, float* __restrict__ R)
{
    const int colg = (t & 31) << 2;
    const int grp  = t >> 5;      // 0..15
    const int m    = grp >> 2;    // 0..3 (3 = idle)
    const int kq   = grp & 3;
    const int k0   = kq << 5;

    float4 acc0 = make_float4(0.f, 0.f, 0.f, 0.f);
    float4 acc1 = make_float4(0.f, 0.f, 0.f, 0.f);
    float4 acc2 = make_float4(0.f, 0.f, 0.f, 0.f);
    float4 acc3 = make_float4(0.f, 0.f, 0.f, 0.f);

    if (m < 3) {
        const float* Wm = (m == 0) ? Wa : (m == 1) ? Wb : Wr;
#pragma unroll 1
        for (int kb = 0; kb < 32; kb += 16) {
            float4 wv[16];
#pragma unroll
            for (int j = 0; j < 16; ++j)
                wv[j] = *(const float4*)(Wm + (size_t)(k0 + kb + j) * HD + colg);
#pragma unroll
            for (int jj = 0; jj < 16; jj += 4) {
                float4 h0 = *(const float4*)&g.hs[0][k0 + kb + jj];
                float4 h1 = *(const float4*)&g.hs[1][k0 + kb + jj];
                float4 h2 = *(const float4*)&g.hs[2][k0 + kb + jj];
                float4 h3 = *(const float4*)&g.hs[3][k0 + kb + jj];
                if (RELU) {
                    h0.x = fmaxf(h0.x, 0.f); h0.y = fmaxf(h0.y, 0.f); h0.z = fmaxf(h0.z, 0.f); h0.w = fmaxf(h0.w, 0.f);
                    h1.x = fmaxf(h1.x, 0.f); h1.y = fmaxf(h1.y, 0.f); h1.z = fmaxf(h1.z, 0.f); h1.w = fmaxf(h1.w, 0.f);
                    h2.x = fmaxf(h2.x, 0.f); h2.y = fmaxf(h2.y, 0.f); h2.z = fmaxf(h2.z, 0.f); h2.w = fmaxf(h2.w, 0.f);
                    h3.x = fmaxf(h3.x, 0.f); h3.y = fmaxf(h3.y, 0.f); h3.z = fmaxf(h3.z, 0.f); h3.w = fmaxf(h3.w, 0.f);
                }
                fma4(acc0, h0.x, wv[jj + 0]); fma4(acc0, h0.y, wv[jj + 1]);
                fma4(acc0, h0.z, wv[jj + 2]); fma4(acc0, h0.w, wv[jj + 3]);
                fma4(acc1, h1.x, wv[jj + 0]); fma4(acc1, h1.y, wv[jj + 1]);
                fma4(acc1, h1.z, wv[jj + 2]); fma4(acc1, h1.w, wv[jj + 3]);
                fma4(acc2, h2.x, wv[jj + 0]); fma4(acc2, h2.y, wv[jj + 1]);
                fma4(acc2, h2.z, wv[jj + 2]); fma4(acc2, h2.w, wv[jj + 3]);
                fma4(acc3, h3.x, wv[jj + 0]); fma4(acc3, h3.y, wv[jj + 1]);
                fma4(acc3, h3.z, wv[jj + 2]); fma4(acc3, h3.w, wv[jj + 3]);
            }
        }
        if (kq != 0) {
            *(float4*)&g.pbuf[kq - 1][m][0][colg] = acc0;
            *(float4*)&g.pbuf[kq - 1][m][1][colg] = acc1;
            *(float4*)&g.pbuf[kq - 1][m][2][colg] = acc2;
            *(float4*)&g.pbuf[kq - 1][m][3][colg] = acc3;
        }
    }
    __syncthreads();
    if (m < 3 && kq == 0) {
#pragma unroll
        for (int pp = 0; pp < 3; ++pp) {
            const float4 p0 = *(const float4*)&g.pbuf[pp][m][0][colg];
            const float4 p1 = *(const float4*)&g.pbuf[pp][m][1][colg];
            const float4 p2 = *(const float4*)&g.pbuf[pp][m][2][colg];
            const float4 p3 = *(const float4*)&g.pbuf[pp][m][3][colg];
            acc0.x += p0.x; acc0.y += p0.y; acc0.z += p0.z; acc0.w += p0.w;
            acc1.x += p1.x; acc1.y += p1.y; acc1.z += p1.z; acc1.w += p1.w;
            acc2.x += p2.x; acc2.y += p2.y; acc2.z += p2.z; acc2.w += p2.w;
            acc3.x += p3.x; acc3.y += p3.y; acc3.z += p3.z; acc3.w += p3.w;
        }
        float* O = (m == 0) ? U : (m == 1) ? V : R;
        if (m == 2) {
            const float4 bv = *(const float4*)(bias + colg);
            acc0.x += bv.x; acc0.y += bv.y; acc0.z += bv.z; acc0.w += bv.w;
            acc1.x += bv.x; acc1.y += bv.y; acc1.z += bv.z; acc1.w += bv.w;
            acc2.x += bv.x; acc2.y += bv.y; acc2.z += bv.z; acc2.w += bv.w;
            acc3.x += bv.x; acc3.y += bv.y; acc3.z += bv.z; acc3.w += bv.w;
        }
        *(float4*)(O + (size_t)(n0 + 0) * HD + colg) = acc0;
        *(float4*)(O + (size_t)(n0 + 1) * HD + colg) = acc1;
        *(float4*)(O + (size_t)(n0 + 2) * HD + colg) = acc2;
        *(float4*)(O + (size_t)(n0 + 3) * HD + colg) = acc3;
    }
}

// ---- G2: scan + persist + layer-1 via P/Q identity + layer-2 GEMMs ----
__global__ __launch_bounds__(NTHR) void g2k(
    const float* __restrict__ x, const int* __restrict__ ei,
    const float* __restrict__ attr,
    const float* __restrict__ lw1, const float* __restrict__ lb1,
    const float* __restrict__ root1, const float* __restrict__ bias1,
    const float* __restrict__ lw2, const float* __restrict__ lb2,
    const float* __restrict__ root2, const float* __restrict__ bias2,
    float* __restrict__ U2, float* __restrict__ V2, float* __restrict__ R2,
    int* __restrict__ gecnt, int* __restrict__ gerow,
    int* __restrict__ gesrc, float* __restrict__ geattr,
    int E)
{
    __shared__ Tile g;
    const int t = threadIdx.x;
    const int n0 = blockIdx.x * TR;

    // zero P/Q sums (ordered before use by scan's first barrier)
    if (t < 2 * (TR + 1) * 2) ((float*)g.p1q1)[t] = 0.f;

    const int pad = scan_edges(ei, attr, E, n0, g, t);

    // persist padded list for g3k/g4k (plain global stores)
    {
        const int base = blockIdx.x * CAPP;
        if (t < pad) {
            gerow[base + t]  = g.lrow[t];
            gesrc[base + t]  = g.lsrc[t];
            geattr[base + t] = g.lattr[t];
        }
        if (t == 0) gecnt[blockIdx.x] = pad;
    }

    // P1,Q1 sums: P[r] += a*x[s], Q[r] += x[s]  (2 components each)
    for (int i = t; i < pad; i += NTHR) {
        const int r = g.lrow[i], s = g.lsrc[i];
        const float a = g.lattr[i];
        const float2 xv = *(const float2*)(x + (size_t)s * 2);
        atomicAdd(&g.p1q1[0][r][0], a * xv.x);
        atomicAdd(&g.p1q1[0][r][1], a * xv.y);
        atomicAdd(&g.p1q1[1][r][0], xv.x);
        atomicAdd(&g.p1q1[1][r][1], xv.y);
    }
    __syncthreads();

    // hs = h1 = relu( x@root1 + bias1 + P@A1 + Q@B1 )   (TR*HD == NTHR)
    {
        const int r = t >> 7, c = t & 127;
        const float x0 = x[(n0 + r) * 2 + 0], x1 = x[(n0 + r) * 2 + 1];
        float v = fmaf(x0, root1[c], fmaf(x1, root1[HD + c], bias1[c]));
        v = fmaf(g.p1q1[0][r][0], lw1[c],      v);
        v = fmaf(g.p1q1[0][r][1], lw1[HD + c], v);
        v = fmaf(g.p1q1[1][r][0], lb1[c],      v);
        v = fmaf(g.p1q1[1][r][1], lb1[HD + c], v);
        g.hs[r][c] = fmaxf(v, 0.f);
    }
    __syncthreads();

    gemm3<false>(g, n0, t, lw2, lb2, root2, bias2, U2, V2, R2);
}

// ---- G3: list-load + layer-2 gather + layer-3 GEMMs ----
__global__ __launch_bounds__(NTHR) void g3k(
    const float* __restrict__ U2, const float* __restrict__ V2,
    const float* __restrict__ R2,
    const float* __restrict__ lw3, const float* __restrict__ lb3,
    const float* __restrict__ root3, const float* __restrict__ bias3,
    float* __restrict__ U3, float* __restrict__ V3, float* __restrict__ R3,
    const int* __restrict__ gecnt, const int* __restrict__ gerow,
    const int* __restrict__ gesrc, const float* __restrict__ geattr)
{
    __shared__ Tile g;
    const int t = threadIdx.x;
    const int n0 = blockIdx.x * TR;

    // hs-init and list-load overlap; one shared barrier.
    if (t < TR * HD / 4)
        ((float4*)&g.hs[0][0])[t] = ((const float4*)(R2 + (size_t)n0 * HD))[t];
    const int pad = gecnt[blockIdx.x];
    {
        const int base = blockIdx.x * CAPP;
        if (t < pad) {
            g.lrow[t]  = gerow[base + t];
            g.lsrc[t]  = gesrc[base + t];
            g.lattr[t] = geattr[base + t];
        }
    }
    __syncthreads();

    gather_uv(U2, V2, g, pad, t);
    gemm3<true>(g, n0, t, lw3, lb3, root3, bias3, U3, V3, R3);
}

// ---- G4: list-load + layer-3 gather -> out (no relu, plain stores) ----
__global__ __launch_bounds__(NTHR) void g4k(
    const float* __restrict__ U3, const float* __restrict__ V3,
    const float* __restrict__ R3, float* __restrict__ out,
    const int* __restrict__ gecnt, const int* __restrict__ gerow,
    const int* __restrict__ gesrc, const float* __restrict__ geattr)
{
    __shared__ Tile g;
    const int t = threadIdx.x;
    const int n0 = blockIdx.x * TR;

    if (t < TR * HD / 4)
        ((float4*)&g.hs[0][0])[t] = ((const float4*)(R3 + (size_t)n0 * HD))[t];
    const int pad = gecnt[blockIdx.x];
    {
        const int base = blockIdx.x * CAPP;
        if (t < pad) {
            g.lrow[t]  = gerow[base + t];
            g.lsrc[t]  = gesrc[base + t];
            g.lattr[t] = geattr[base + t];
        }
    }
    __syncthreads();

    gather_uv(U3, V3, g, pad, t);

    if (t < TR * HD / 4)
        ((float4*)(out + (size_t)n0 * HD))[t] = ((const float4*)&g.hs[0][0])[t];
}

extern "C" void kernel_launch(void* const* d_in, const int* in_sizes, int n_in,
                              void* d_out, int out_size, void* d_ws, size_t ws_size,
                              hipStream_t stream) {
    const float* x     = (const float*)d_in[0];
    const int*   ei    = (const int*)  d_in[1];
    const float* attr  = (const float*)d_in[2];
    const float* lw1   = (const float*)d_in[3];
    const float* lb1   = (const float*)d_in[4];
    const float* root1 = (const float*)d_in[5];
    const float* bias1 = (const float*)d_in[6];
    const float* lw2   = (const float*)d_in[7];
    const float* lb2   = (const float*)d_in[8];
    const float* root2 = (const float*)d_in[9];
    const float* bias2 = (const float*)d_in[10];
    const float* lw3   = (const float*)d_in[11];
    const float* lb3   = (const float*)d_in[12];
    const float* root3 = (const float*)d_in[13];
    const float* bias3 = (const float*)d_in[14];

    const int N = in_sizes[0] / 2;   // x: [N,2]
    const int E = in_sizes[1] / 2;   // edge_index: [2,E]
    const int ntiles = N / TR;       // 256 blocks, ~1 per CU

    float* out = (float*)d_out;
    float* ws  = (float*)d_ws;
    float* U2 = ws + 0 * (size_t)N * HD;
    float* V2 = ws + 1 * (size_t)N * HD;
    float* R2 = ws + 2 * (size_t)N * HD;
    float* U3 = ws + 3 * (size_t)N * HD;
    float* V3 = ws + 4 * (size_t)N * HD;
    float* R3 = ws + 5 * (size_t)N * HD;
    int*   gecnt  = (int*)(ws + 6 * (size_t)N * HD);
    int*   gerow  = gecnt + ntiles;
    int*   gesrc  = gerow + (size_t)ntiles * CAPP;
    float* geattr = (float*)(gesrc + (size_t)ntiles * CAPP);

    g2k<<<ntiles, NTHR, 0, stream>>>(x, ei, attr, lw1, lb1, root1, bias1,
                                     lw2, lb2, root2, bias2, U2, V2, R2,
                                     gecnt, gerow, gesrc, geattr, E);
    g3k<<<ntiles, NTHR, 0, stream>>>(U2, V2, R2, lw3, lb3, root3, bias3,
                                     U3, V3, R3, gecnt, gerow, gesrc, geattr);
    g4k<<<ntiles, NTHR, 0, stream>>>(U3, V3, R3, out,
                                     gecnt, gerow, gesrc, geattr);
}